// Round 7
// baseline (505.642 us; speedup 1.0000x reference)
//
#include <hip/hip_runtime.h>
#include <stdint.h>
#include <math.h>

#define BB 4
#define CC 21
#define NN 4096
#define NITER 5
#define PH 64     // m per staged phase = one image row
#define PCH 22    // channels (21 + ones/norm)
#define PROW 72   // padded pB LDS row (ushorts) = 144 B

// exp(-0.5*d2/theta^2) = exp2(coef*d2) ; rgb prescaled so |dg|^2 is the exponent
#define CS_COEF  (-0.08014972449383172f)      // spatial: -0.5*log2e/9
#define CBC_COEF (-2.8177637517362567e-05f)   // bilateral coords: -0.5*log2e/160^2
#define SB_SCALE (0.28310726680985215f)       // rgb prescale: sqrt(0.5*log2e)/3

typedef _Float16 f16x8 __attribute__((ext_vector_type(8)));
typedef float f32x16 __attribute__((ext_vector_type(16)));
typedef uint32_t u32;
typedef uint32_t u32x4 __attribute__((ext_vector_type(4)));

static __device__ __forceinline__ u32 pk2(float a, float b) {
  return __builtin_bit_cast(u32, __builtin_amdgcn_cvt_pkrtz(a, b));  // v_cvt_pkrtz_f16_f32
}
static __device__ __forceinline__ f16x8 mk8(u32 a, u32 b, u32 c, u32 d) {
  u32x4 t = {a, b, c, d};
  return __builtin_bit_cast(f16x8, t);
}

// grid (nmc, 32, B), block 256 = 4 waves; wave owns a 32-n tile.
// D = K(32n x 16m) . P(16m x 32ch); A row = lane&31 = n-local, B col = lane&31 = ch,
// k = (lane>>5)*8 + elem for both (shared k-permutation cancels).
__global__ __launch_bounds__(256) void crf_filter(const float* __restrict__ grec,
                                                  const _Float16* __restrict__ pB,
                                                  float* __restrict__ part,
                                                  int mlen, int nmc) {
  __shared__ float g_lds[2][PH * 4];          // 2 x 1 KB
  __shared__ _Float16 p_lds[2][PCH * PROW];   // 2 x 3168 B (padded rows)

  const int chunk = blockIdx.x, ng = blockIdx.y, b = blockIdx.z;
  const int tid = threadIdx.x;
  const int wave = tid >> 6, lane = tid & 63;
  const int c = lane & 31, h = lane >> 5;
  const int ce = (c < PCH) ? c : (PCH - 1);   // clamp B row for lanes c>=22
  const int ntile = ng * 4 + wave;
  const int n = (ntile << 5) + c;
  const float xn = (float)(n & 63);
  const float yn = (float)(n >> 6);           // wave-uniform: tile spans half a row
  const float xh = xn - (float)(h << 3);      // xn - 8h

  const float* grecb = grec + (size_t)b * NN * 4;
  const _Float16* pBb = pB + (size_t)b * PCH * NN;
  const float4 gn = *(const float4*)(grecb + (size_t)n * 4);
  const float gr2 = 2.f * gn.x, gg2 = 2.f * gn.y, gb2 = 2.f * gn.z;

  // spatial x-factors: per step s, x-offsets = s*16 + 8h + j ; identical every row.
  f16x8 sxa[4];
#pragma unroll
  for (int q = 0; q < 4; ++q) {
    u32 w[4];
#pragma unroll
    for (int jp = 0; jp < 4; ++jp) {
      const float d0 = xh - (float)(q * 16 + 2 * jp);
      const float d1 = d0 - 1.f;
      w[jp] = pk2(__builtin_amdgcn_exp2f(CS_COEF * d0 * d0),
                  __builtin_amdgcn_exp2f(CS_COEF * d1 * d1));
    }
    sxa[q] = mk8(w[0], w[1], w[2], w[3]);
  }

  f32x16 accs, accb, rowacc;
#pragma unroll
  for (int r = 0; r < 16; ++r) { accs[r] = 0.f; accb[r] = 0.f; rowacc[r] = 0.f; }

  const int m_lo = chunk * mlen;
  const int phases = mlen / PH;

  // staging roles: t<64 -> g (1 float4), 64<=t<240 -> pB (1 float4)
  const int pidx = tid - 64;
  const int pch = pidx >> 3, po = pidx & 7;
  float4 stv;
  {
    if (tid < 64) stv = *(const float4*)(grecb + (size_t)(m_lo + tid) * 4);
    else if (tid < 240) stv = *(const float4*)(pBb + (size_t)pch * NN + m_lo + po * 8);
  }

  for (int p = 0; p < phases; ++p) {
    const int bsel = p & 1;
    if (tid < 64) *(float4*)&g_lds[bsel][tid * 4] = stv;
    else if (tid < 240) *(float4*)&p_lds[bsel][pch * PROW + po * 8] = stv;
    __syncthreads();
    if (p + 1 < phases) {
      const int mb = m_lo + (p + 1) * PH;
      if (tid < 64) stv = *(const float4*)(grecb + (size_t)(mb + tid) * 4);
      else if (tid < 240) stv = *(const float4*)(pBb + (size_t)pch * NN + mb + po * 8);
    }

    const int row = (m_lo >> 6) + p;
    const float dy = yn - (float)row;
    const float dy2 = dy * dy;
    const float sy = __builtin_amdgcn_exp2f(CS_COEF * dy2);
    const float crow = fmaf(CBC_COEF, dy2, gn.w);  // CBC*dy^2 - |g_n|^2

    const float* gbuf = g_lds[bsel];
    const _Float16* pbuf = p_lds[bsel];
#pragma unroll
    for (int s = 0; s < 4; ++s) {
      float kb[8];
#pragma unroll
      for (int j = 0; j < 8; ++j) {
        const int idx = s * 16 + (h << 3) + j;
        const float4 gm = *(const float4*)&gbuf[idx * 4];
        const float dxa = xh - (float)(s * 16 + j);
        const float u = CBC_COEF * dxa;
        float t = gm.w + crow;
        t = fmaf(gr2, gm.x, t);
        t = fmaf(gg2, gm.y, t);
        t = fmaf(gb2, gm.z, t);
        kb[j] = __builtin_amdgcn_exp2f(fmaf(u, dxa, t));
      }
      const f16x8 Ab = mk8(pk2(kb[0], kb[1]), pk2(kb[2], kb[3]),
                           pk2(kb[4], kb[5]), pk2(kb[6], kb[7]));
      const f16x8 Bf = *(const f16x8*)&pbuf[ce * PROW + s * 16 + (h << 3)];
      rowacc = __builtin_amdgcn_mfma_f32_32x32x16_f16(sxa[s], Bf, rowacc, 0, 0, 0);
      accb = __builtin_amdgcn_mfma_f32_32x32x16_f16(Ab, Bf, accb, 0, 0, 0);
    }
    // fold the row's spatial contribution: accs += sy * rowacc
#pragma unroll
    for (int r = 0; r < 16; ++r) {
      accs[r] = fmaf(sy, rowacc[r], accs[r]);
      rowacc[r] = 0.f;
    }
    __syncthreads();
  }

  // part[((chunk*B + b)*2 + mat)][ch][n] ; coalesced for the update kernel
  if (c < PCH) {
    float* os = part + (((size_t)(chunk * BB + b) * 2) * PCH + c) * NN + (ntile << 5) + (h << 2);
    float* ob = os + (size_t)PCH * NN;
#pragma unroll
    for (int g4 = 0; g4 < 4; ++g4) {
      *(float4*)(os + g4 * 8) = make_float4(accs[4 * g4], accs[4 * g4 + 1],
                                            accs[4 * g4 + 2], accs[4 * g4 + 3]);
      *(float4*)(ob + g4 * 8) = make_float4(accb[4 * g4], accb[4 * g4 + 1],
                                            accb[4 * g4 + 2], accb[4 * g4 + 3]);
    }
  }
}

__global__ __launch_bounds__(256) void crf_update(const float* __restrict__ unary,
                                                  const float* __restrict__ rgb,
                                                  const float* __restrict__ Ws,
                                                  const float* __restrict__ Wb,
                                                  const float* __restrict__ Cm,
                                                  const float* __restrict__ part,
                                                  float* __restrict__ grec,
                                                  _Float16* __restrict__ pB,
                                                  float* __restrict__ dout,
                                                  int first, int last, int nmc) {
  const int tid = blockIdx.x * 256 + threadIdx.x;  // b*4096+n
  const int b = tid >> 12, n = tid & 4095;
  const float* up = unary + (size_t)tid * CC;

  float q[CC];
  if (!first) {
    float sp[PCH], bl[PCH];
#pragma unroll
    for (int c = 0; c < PCH; ++c) { sp[c] = 0.f; bl[c] = 0.f; }
    for (int ch = 0; ch < nmc; ++ch) {
      const float* p0 = part + (((size_t)(ch * BB + b) * 2) * PCH) * NN + n;
      const float* p1 = p0 + (size_t)PCH * NN;
#pragma unroll
      for (int c = 0; c < PCH; ++c) {
        sp[c] += p0[(size_t)c * NN];
        bl[c] += p1[(size_t)c * NN];
      }
    }
    const float isn = 1.f / sp[21], ibn = 1.f / bl[21];
#pragma unroll
    for (int c = 0; c < CC; ++c) { sp[c] *= isn; bl[c] *= ibn; }
    float msg[CC];
    for (int c = 0; c < CC; ++c) {
      float a = 0.f;
      for (int k = 0; k < CC; ++k)
        a += Ws[c * CC + k] * sp[k] + Wb[c * CC + k] * bl[k];
      msg[c] = a;
    }
    for (int c = 0; c < CC; ++c) {
      float a = 0.f;
      for (int k = 0; k < CC; ++k) a += Cm[c * CC + k] * msg[k];
      q[c] = up[c] - a;
    }
  } else {
#pragma unroll
    for (int c = 0; c < CC; ++c) q[c] = up[c];
  }

  if (last) {
    float* op = dout + (size_t)tid * CC;
#pragma unroll
    for (int c = 0; c < CC; ++c) op[c] = q[c];
  }

  float mx = q[0];
#pragma unroll
  for (int c = 1; c < CC; ++c) mx = fmaxf(mx, q[c]);
  float e[CC], s = 0.f;
#pragma unroll
  for (int c = 0; c < CC; ++c) { e[c] = __expf(q[c] - mx); s += e[c]; }
  const float is = 1.f / s;

  // g-record: rgb*SB and -|g|^2 (dot-form bilateral exponent)
  const float* rg = rgb + (size_t)tid * 3;
  const float g0 = rg[0] * SB_SCALE, g1 = rg[1] * SB_SCALE, g2 = rg[2] * SB_SCALE;
  *(float4*)(grec + (size_t)tid * 4) =
      make_float4(g0, g1, g2, -fmaf(g2, g2, fmaf(g1, g1, g0 * g0)));

  // transposed f16 p + ones row (norm channel)
  _Float16* pb = pB + (size_t)b * PCH * NN + n;
#pragma unroll
  for (int c = 0; c < CC; ++c) pb[(size_t)c * NN] = (_Float16)(e[c] * is);
  pb[(size_t)21 * NN] = (_Float16)1.0f;
}

extern "C" void kernel_launch(void* const* d_in, const int* in_sizes, int n_in,
                              void* d_out, int out_size, void* d_ws, size_t ws_size,
                              hipStream_t stream) {
  const float* unary = (const float*)d_in[0];
  const float* rgb   = (const float*)d_in[1];
  const float* Ws    = (const float*)d_in[2];
  const float* Wb    = (const float*)d_in[3];
  const float* Cm    = (const float*)d_in[4];
  float* out = (float*)d_out;

  float* grec = (float*)d_ws;                                 // [B][N][4] f32 = 256 KB
  const size_t grec_bytes = (size_t)BB * NN * 4 * 4;
  _Float16* pB = (_Float16*)((char*)d_ws + grec_bytes);       // [B][22][N] f16 = 736 KB
  const size_t pB_bytes = (size_t)BB * PCH * NN * 2;

  int nmc = 8;
  while (nmc > 1 &&
         ws_size < grec_bytes + pB_bytes + (size_t)nmc * BB * 2 * PCH * NN * 4)
    nmc >>= 1;
  const int mlen = NN / nmc;
  float* part = (float*)((char*)d_ws + grec_bytes + pB_bytes); // [nmc*B*2][22][N]

  crf_update<<<dim3(64), dim3(256), 0, stream>>>(unary, rgb, Ws, Wb, Cm,
                                                 part, grec, pB, out, 1, 0, nmc);
  for (int it = 0; it < NITER; ++it) {
    crf_filter<<<dim3(nmc, 32, BB), dim3(256), 0, stream>>>(grec, pB, part, mlen, nmc);
    crf_update<<<dim3(64), dim3(256), 0, stream>>>(unary, rgb, Ws, Wb, Cm,
                                                   part, grec, pB, out, 0,
                                                   (it == NITER - 1) ? 1 : 0, nmc);
  }
}

// Round 9
// 334.304 us; speedup vs baseline: 1.5125x; 1.5125x over previous
//
#include <hip/hip_runtime.h>
#include <stdint.h>
#include <math.h>

#define BB 4
#define CC 21
#define NN 4096
#define NITER 5
#define PH 64     // m per staged phase = one image row
#define PCH 22    // channels (21 + ones/norm)
#define PROW 72   // padded pB LDS row (ushorts) = 144 B

// exp(-0.5*d2/theta^2) = exp2(coef*d2) ; rgb prescaled so |dg|^2 is the exponent
#define CS_COEF  (-0.08014972449383172f)      // spatial: -0.5*log2e/9
#define CBC_COEF (-2.8177637517362567e-05f)   // bilateral coords: -0.5*log2e/160^2
#define SB_SCALE (0.28310726680985215f)       // rgb prescale: sqrt(0.5*log2e)/3

typedef _Float16 f16x8 __attribute__((ext_vector_type(8)));
typedef float f32x16 __attribute__((ext_vector_type(16)));
typedef uint32_t u32;
typedef uint32_t u32x4 __attribute__((ext_vector_type(4)));

static __device__ __forceinline__ u32 pk2(float a, float b) {
  return __builtin_bit_cast(u32, __builtin_amdgcn_cvt_pkrtz(a, b));  // v_cvt_pkrtz_f16_f32
}
static __device__ __forceinline__ f16x8 mk8(u32 a, u32 b, u32 c, u32 d) {
  u32x4 t = {a, b, c, d};
  return __builtin_bit_cast(f16x8, t);
}

// grid (nmc, 32, B), block 256 = 4 waves; wave owns a 32-n tile.
// D = K(32n x 16m) . P(16m x 32ch); A row = lane&31 = n-local, B col = lane&31 = ch,
// k = (lane>>5)*8 + elem for both (shared k-permutation cancels).
__global__ __launch_bounds__(256) void crf_filter(const float* __restrict__ grec,
                                                  const _Float16* __restrict__ pB,
                                                  float* __restrict__ part,
                                                  int mlen, int nmc) {
  __shared__ float g_lds[2][PH * 4];          // 2 x 1 KB
  __shared__ _Float16 p_lds[2][PCH * PROW];   // 2 x 3168 B (padded rows)

  const int chunk = blockIdx.x, ng = blockIdx.y, b = blockIdx.z;
  const int tid = threadIdx.x;
  const int wave = tid >> 6, lane = tid & 63;
  const int c = lane & 31, h = lane >> 5;
  const int ce = (c < PCH) ? c : (PCH - 1);   // clamp B row for lanes c>=22
  const int ntile = ng * 4 + wave;
  const int n = (ntile << 5) + c;
  const float xn = (float)(n & 63);
  const float yn = (float)(n >> 6);           // wave-uniform: tile spans half a row
  const float xh = xn - (float)(h << 3);      // xn - 8h

  const float* grecb = grec + (size_t)b * NN * 4;
  const _Float16* pBb = pB + (size_t)b * PCH * NN;
  const float4 gn = *(const float4*)(grecb + (size_t)n * 4);
  const float gr2 = 2.f * gn.x, gg2 = 2.f * gn.y, gb2 = 2.f * gn.z;

  // spatial x-factors: per step s, x-offsets = s*16 + 8h + j ; identical every row.
  f16x8 sxa[4];
#pragma unroll
  for (int q = 0; q < 4; ++q) {
    u32 w[4];
#pragma unroll
    for (int jp = 0; jp < 4; ++jp) {
      const float d0 = xh - (float)(q * 16 + 2 * jp);
      const float d1 = d0 - 1.f;
      w[jp] = pk2(__builtin_amdgcn_exp2f(CS_COEF * d0 * d0),
                  __builtin_amdgcn_exp2f(CS_COEF * d1 * d1));
    }
    sxa[q] = mk8(w[0], w[1], w[2], w[3]);
  }

  f32x16 accs, accb, rowacc;
#pragma unroll
  for (int r = 0; r < 16; ++r) { accs[r] = 0.f; accb[r] = 0.f; rowacc[r] = 0.f; }

  const int m_lo = chunk * mlen;
  const int phases = mlen / PH;

  // staging roles: t<64 -> g (1 float4), 64<=t<240 -> pB (1 float4)
  const int pidx = tid - 64;
  const int pch = pidx >> 3, po = pidx & 7;
  float4 stv;
  {
    if (tid < 64) stv = *(const float4*)(grecb + (size_t)(m_lo + tid) * 4);
    else if (tid < 240) stv = *(const float4*)(pBb + (size_t)pch * NN + m_lo + po * 8);
  }

  for (int p = 0; p < phases; ++p) {
    const int bsel = p & 1;
    if (tid < 64) *(float4*)&g_lds[bsel][tid * 4] = stv;
    else if (tid < 240) *(float4*)&p_lds[bsel][pch * PROW + po * 8] = stv;
    __syncthreads();
    if (p + 1 < phases) {
      const int mb = m_lo + (p + 1) * PH;
      if (tid < 64) stv = *(const float4*)(grecb + (size_t)(mb + tid) * 4);
      else if (tid < 240) stv = *(const float4*)(pBb + (size_t)pch * NN + mb + po * 8);
    }

    const int row = (m_lo >> 6) + p;
    const float dy = yn - (float)row;
    const float dy2 = dy * dy;
    const float sy = __builtin_amdgcn_exp2f(CS_COEF * dy2);
    const float crow = fmaf(CBC_COEF, dy2, gn.w);  // CBC*dy^2 - |g_n|^2

    const float* gbuf = g_lds[bsel];
    const _Float16* pbuf = p_lds[bsel];
#pragma unroll
    for (int s = 0; s < 4; ++s) {
      float kb[8];
#pragma unroll
      for (int j = 0; j < 8; ++j) {
        const int idx = s * 16 + (h << 3) + j;
        const float4 gm = *(const float4*)&gbuf[idx * 4];
        const float dxa = xh - (float)(s * 16 + j);
        const float u = CBC_COEF * dxa;
        float t = gm.w + crow;
        t = fmaf(gr2, gm.x, t);
        t = fmaf(gg2, gm.y, t);
        t = fmaf(gb2, gm.z, t);
        kb[j] = __builtin_amdgcn_exp2f(fmaf(u, dxa, t));
      }
      const f16x8 Ab = mk8(pk2(kb[0], kb[1]), pk2(kb[2], kb[3]),
                           pk2(kb[4], kb[5]), pk2(kb[6], kb[7]));
      const f16x8 Bf = *(const f16x8*)&pbuf[ce * PROW + s * 16 + (h << 3)];
      rowacc = __builtin_amdgcn_mfma_f32_32x32x16_f16(sxa[s], Bf, rowacc, 0, 0, 0);
      accb = __builtin_amdgcn_mfma_f32_32x32x16_f16(Ab, Bf, accb, 0, 0, 0);
    }
    // fold the row's spatial contribution: accs += sy * rowacc
#pragma unroll
    for (int r = 0; r < 16; ++r) {
      accs[r] = fmaf(sy, rowacc[r], accs[r]);
      rowacc[r] = 0.f;
    }
    __syncthreads();
  }

  // part[((chunk*B + b)*2 + mat)][ch][n]
  if (c < PCH) {
    float* os = part + (((size_t)(chunk * BB + b) * 2) * PCH + c) * NN + (ntile << 5) + (h << 2);
    float* ob = os + (size_t)PCH * NN;
#pragma unroll
    for (int g4 = 0; g4 < 4; ++g4) {
      *(float4*)(os + g4 * 8) = make_float4(accs[4 * g4], accs[4 * g4 + 1],
                                            accs[4 * g4 + 2], accs[4 * g4 + 3]);
      *(float4*)(ob + g4 * 8) = make_float4(accb[4 * g4], accb[4 * g4 + 1],
                                            accb[4 * g4 + 2], accb[4 * g4 + 3]);
    }
  }
}

// Sum the nmc chunk partials in-place into chunk 0's region.
// One float4 output per thread; fully parallel (720896 f32 -> 180224 threads).
__global__ __launch_bounds__(256) void crf_reduce(float* __restrict__ part, int nmc) {
  const size_t i = (size_t)blockIdx.x * 256 + threadIdx.x;   // float4 index
  const size_t stride4 = (size_t)BB * 2 * PCH * NN / 4;      // chunk stride (f4)
  float4* p = (float4*)part + i;
  float4 a = p[0];
  for (int ch = 1; ch < nmc; ++ch) {
    const float4 v = p[(size_t)ch * stride4];
    a.x += v.x; a.y += v.y; a.z += v.z; a.w += v.w;
  }
  p[0] = a;
}

__global__ __launch_bounds__(256) void crf_update(const float* __restrict__ unary,
                                                  const float* __restrict__ rgb,
                                                  const float* __restrict__ Ws,
                                                  const float* __restrict__ Wb,
                                                  const float* __restrict__ Cm,
                                                  const float* __restrict__ part,
                                                  float* __restrict__ grec,
                                                  _Float16* __restrict__ pB,
                                                  float* __restrict__ dout,
                                                  int first, int last) {
  const int tid = blockIdx.x * 256 + threadIdx.x;  // b*4096+n
  const int b = tid >> 12, n = tid & 4095;
  const float* up = unary + (size_t)tid * CC;

  float q[CC];
  if (!first) {
    float sp[PCH], bl[PCH];
    // reduced partials live in chunk 0: ((b*2+mat)*PCH+c)*NN + n
    const float* p0 = part + ((size_t)b * 2 * PCH) * NN + n;
    const float* p1 = p0 + (size_t)PCH * NN;
#pragma unroll
    for (int c = 0; c < PCH; ++c) {
      sp[c] = p0[(size_t)c * NN];
      bl[c] = p1[(size_t)c * NN];
    }
    const float isn = 1.f / sp[21], ibn = 1.f / bl[21];
#pragma unroll
    for (int c = 0; c < CC; ++c) { sp[c] *= isn; bl[c] *= ibn; }
    float msg[CC];
    for (int c = 0; c < CC; ++c) {
      float a = 0.f;
      for (int k = 0; k < CC; ++k)
        a += Ws[c * CC + k] * sp[k] + Wb[c * CC + k] * bl[k];
      msg[c] = a;
    }
    for (int c = 0; c < CC; ++c) {
      float a = 0.f;
      for (int k = 0; k < CC; ++k) a += Cm[c * CC + k] * msg[k];
      q[c] = up[c] - a;
    }
  } else {
#pragma unroll
    for (int c = 0; c < CC; ++c) q[c] = up[c];
  }

  if (last) {
    float* op = dout + (size_t)tid * CC;
#pragma unroll
    for (int c = 0; c < CC; ++c) op[c] = q[c];
  }

  float mx = q[0];
#pragma unroll
  for (int c = 1; c < CC; ++c) mx = fmaxf(mx, q[c]);
  float e[CC], s = 0.f;
#pragma unroll
  for (int c = 0; c < CC; ++c) { e[c] = __expf(q[c] - mx); s += e[c]; }
  const float is = 1.f / s;

  // g-record: rgb*SB and -|g|^2 (dot-form bilateral exponent)
  const float* rg = rgb + (size_t)tid * 3;
  const float g0 = rg[0] * SB_SCALE, g1 = rg[1] * SB_SCALE, g2 = rg[2] * SB_SCALE;
  *(float4*)(grec + (size_t)tid * 4) =
      make_float4(g0, g1, g2, -fmaf(g2, g2, fmaf(g1, g1, g0 * g0)));

  // transposed f16 p + ones row (norm channel)
  _Float16* pb = pB + (size_t)b * PCH * NN + n;
#pragma unroll
  for (int c = 0; c < CC; ++c) pb[(size_t)c * NN] = (_Float16)(e[c] * is);
  pb[(size_t)21 * NN] = (_Float16)1.0f;
}

extern "C" void kernel_launch(void* const* d_in, const int* in_sizes, int n_in,
                              void* d_out, int out_size, void* d_ws, size_t ws_size,
                              hipStream_t stream) {
  const float* unary = (const float*)d_in[0];
  const float* rgb   = (const float*)d_in[1];
  const float* Ws    = (const float*)d_in[2];
  const float* Wb    = (const float*)d_in[3];
  const float* Cm    = (const float*)d_in[4];
  float* out = (float*)d_out;

  float* grec = (float*)d_ws;                                 // [B][N][4] f32 = 256 KB
  const size_t grec_bytes = (size_t)BB * NN * 4 * 4;
  _Float16* pB = (_Float16*)((char*)d_ws + grec_bytes);       // [B][22][N] f16 = 736 KB
  const size_t pB_bytes = (size_t)BB * PCH * NN * 2;

  int nmc = 8;
  while (nmc > 1 &&
         ws_size < grec_bytes + pB_bytes + (size_t)nmc * BB * 2 * PCH * NN * 4)
    nmc >>= 1;
  const int mlen = NN / nmc;
  float* part = (float*)((char*)d_ws + grec_bytes + pB_bytes); // [nmc][B][2][22][N]

  const int red_blocks = (BB * 2 * PCH * NN / 4) / 256;        // 704

  crf_update<<<dim3(64), dim3(256), 0, stream>>>(unary, rgb, Ws, Wb, Cm,
                                                 part, grec, pB, out, 1, 0);
  for (int it = 0; it < NITER; ++it) {
    crf_filter<<<dim3(nmc, 32, BB), dim3(256), 0, stream>>>(grec, pB, part, mlen, nmc);
    crf_reduce<<<dim3(red_blocks), dim3(256), 0, stream>>>(part, nmc);
    crf_update<<<dim3(64), dim3(256), 0, stream>>>(unary, rgb, Ws, Wb, Cm,
                                                   part, grec, pB, out, 0,
                                                   (it == NITER - 1) ? 1 : 0);
  }
}

// Round 12
// 320.330 us; speedup vs baseline: 1.5785x; 1.0436x over previous
//
#include <hip/hip_runtime.h>
#include <stdint.h>
#include <math.h>

#define BB 4
#define CC 21
#define NN 4096
#define NITER 5
#define PH 64     // m per staged phase = one image row
#define PCH 22    // channels (21 + ones/norm)
#define PROW 72   // padded pB LDS row (ushorts) = 144 B
#define CWR 24    // padded CW row (floats, 16B-aligned)

// exp(-0.5*d2/theta^2) = exp2(coef*d2) ; rgb prescaled so |dg|^2 is the exponent
#define CS_COEF  (-0.08014972449383172f)      // spatial: -0.5*log2e/9
#define CBC_COEF (-2.8177637517362567e-05f)   // bilateral coords: -0.5*log2e/160^2
#define SB_SCALE (0.28310726680985215f)       // rgb prescale: sqrt(0.5*log2e)/3

typedef _Float16 f16x8 __attribute__((ext_vector_type(8)));
typedef float f32x16 __attribute__((ext_vector_type(16)));
typedef uint32_t u32;
typedef uint32_t u32x4 __attribute__((ext_vector_type(4)));

static __device__ __forceinline__ u32 pk2(float a, float b) {
  return __builtin_bit_cast(u32, __builtin_amdgcn_cvt_pkrtz(a, b));  // v_cvt_pkrtz_f16_f32
}
static __device__ __forceinline__ f16x8 mk8(u32 a, u32 b, u32 c, u32 d) {
  u32x4 t = {a, b, c, d};
  return __builtin_bit_cast(f16x8, t);
}

// CWT[k][c] = sum_j Cm[c][j] * W[j][k]  (transposed, rows padded to CWR)
__global__ __launch_bounds__(512) void crf_prep(const float* __restrict__ Ws,
                                                const float* __restrict__ Wb,
                                                const float* __restrict__ Cm,
                                                float* __restrict__ CW) {
  const int t = threadIdx.x;
  if (t < 441) {
    const int c = t / 21, k = t % 21;
    float as = 0.f, ab = 0.f;
    for (int j = 0; j < 21; ++j) {
      as += Cm[c * 21 + j] * Ws[j * 21 + k];
      ab += Cm[c * 21 + j] * Wb[j * 21 + k];
    }
    CW[k * CWR + c] = as;               // CWTs
    CW[21 * CWR + k * CWR + c] = ab;    // CWTb
  }
}

// grid (nmc, 32, B), block 256 = 4 waves; wave owns a 32-n tile.
__global__ __launch_bounds__(256) void crf_filter(const float* __restrict__ grec,
                                                  const _Float16* __restrict__ pB,
                                                  float* __restrict__ part,
                                                  int mlen, int nmc) {
  __shared__ float g_lds[2][PH * 4];          // 2 x 1 KB
  __shared__ _Float16 p_lds[2][PCH * PROW];   // 2 x 3168 B (padded rows)

  const int chunk = blockIdx.x, ng = blockIdx.y, b = blockIdx.z;
  const int tid = threadIdx.x;
  const int wave = tid >> 6, lane = tid & 63;
  const int c = lane & 31, h = lane >> 5;
  const int ce = (c < PCH) ? c : (PCH - 1);
  const int ntile = ng * 4 + wave;
  const int n = (ntile << 5) + c;
  const float xn = (float)(n & 63);
  const float yn = (float)(n >> 6);           // wave-uniform
  const float xh = xn - (float)(h << 3);

  const float* grecb = grec + (size_t)b * NN * 4;
  const _Float16* pBb = pB + (size_t)b * PCH * NN;
  const float4 gn = *(const float4*)(grecb + (size_t)n * 4);
  const float gr2 = 2.f * gn.x, gg2 = 2.f * gn.y, gb2 = 2.f * gn.z;

  // spatial x-factors and per-lane CBC*dx^2 constants (loop-invariant)
  f16x8 sxa[4];
  float cdx2v[32];
#pragma unroll
  for (int q = 0; q < 4; ++q) {
    u32 w[4];
#pragma unroll
    for (int jp = 0; jp < 4; ++jp) {
      const float d0 = xh - (float)(q * 16 + 2 * jp);
      const float d1 = d0 - 1.0f;
      w[jp] = pk2(__builtin_amdgcn_exp2f(CS_COEF * d0 * d0),
                  __builtin_amdgcn_exp2f(CS_COEF * d1 * d1));
      cdx2v[q * 8 + 2 * jp]     = CBC_COEF * d0 * d0;
      cdx2v[q * 8 + 2 * jp + 1] = CBC_COEF * d1 * d1;
    }
    sxa[q] = mk8(w[0], w[1], w[2], w[3]);
  }

  f32x16 accs, accb, rowacc;
#pragma unroll
  for (int r = 0; r < 16; ++r) { accs[r] = 0.f; accb[r] = 0.f; rowacc[r] = 0.f; }

  const int m_lo = chunk * mlen;
  const int phases = mlen / PH;

  const int pidx = tid - 64;
  const int pch = pidx >> 3, po = pidx & 7;
  float4 stv;
  {
    if (tid < 64) stv = *(const float4*)(grecb + (size_t)(m_lo + tid) * 4);
    else if (tid < 240) stv = *(const float4*)(pBb + (size_t)pch * NN + m_lo + po * 8);
  }

  for (int p = 0; p < phases; ++p) {
    const int bsel = p & 1;
    if (tid < 64) *(float4*)&g_lds[bsel][tid * 4] = stv;
    else if (tid < 240) *(float4*)&p_lds[bsel][pch * PROW + po * 8] = stv;
    __syncthreads();
    if (p + 1 < phases) {
      const int mb = m_lo + (p + 1) * PH;
      if (tid < 64) stv = *(const float4*)(grecb + (size_t)(mb + tid) * 4);
      else if (tid < 240) stv = *(const float4*)(pBb + (size_t)pch * NN + mb + po * 8);
    }

    const int row = (m_lo >> 6) + p;
    const float dy = yn - (float)row;
    const float dy2 = dy * dy;
    const float sy = __builtin_amdgcn_exp2f(CS_COEF * dy2);
    const float crow = fmaf(CBC_COEF, dy2, gn.w);  // CBC*dy^2 - |g_n|^2

    const float* gbuf = g_lds[bsel];
    const _Float16* pbuf = p_lds[bsel];
#pragma unroll
    for (int s = 0; s < 4; ++s) {
      float kb[8];
#pragma unroll
      for (int j = 0; j < 8; ++j) {
        const int idx = s * 16 + (h << 3) + j;
        const float4 gm = *(const float4*)&gbuf[idx * 4];
        float t = cdx2v[s * 8 + j] + crow;
        t = fmaf(gr2, gm.x, t);
        t = fmaf(gg2, gm.y, t);
        t = fmaf(gb2, gm.z, t);
        kb[j] = __builtin_amdgcn_exp2f(t + gm.w);
      }
      const f16x8 Ab = mk8(pk2(kb[0], kb[1]), pk2(kb[2], kb[3]),
                           pk2(kb[4], kb[5]), pk2(kb[6], kb[7]));
      const f16x8 Bf = *(const f16x8*)&pbuf[ce * PROW + s * 16 + (h << 3)];
      rowacc = __builtin_amdgcn_mfma_f32_32x32x16_f16(sxa[s], Bf, rowacc, 0, 0, 0);
      accb = __builtin_amdgcn_mfma_f32_32x32x16_f16(Ab, Bf, accb, 0, 0, 0);
    }
#pragma unroll
    for (int r = 0; r < 16; ++r) {
      accs[r] = fmaf(sy, rowacc[r], accs[r]);
      rowacc[r] = 0.f;
    }
    __syncthreads();
  }

  // part[chunk][b][mat][ch][n]
  if (c < PCH) {
    float* os = part + (((size_t)(chunk * BB + b) * 2) * PCH + c) * NN + (ntile << 5) + (h << 2);
    float* ob = os + (size_t)PCH * NN;
#pragma unroll
    for (int g4 = 0; g4 < 4; ++g4) {
      *(float4*)(os + g4 * 8) = make_float4(accs[4 * g4], accs[4 * g4 + 1],
                                            accs[4 * g4 + 2], accs[4 * g4 + 3]);
      *(float4*)(ob + g4 * 8) = make_float4(accb[4 * g4], accb[4 * g4 + 1],
                                            accb[4 * g4 + 2], accb[4 * g4 + 3]);
    }
  }
}

// 4 threads per pixel (k-split); reads all nmc chunks directly (fused reduce).
__global__ __launch_bounds__(256) void crf_update(const float* __restrict__ unary,
                                                  const float* __restrict__ rgb,
                                                  const float* __restrict__ CW,
                                                  const float* __restrict__ part,
                                                  float* __restrict__ grec,
                                                  _Float16* __restrict__ pB,
                                                  float* __restrict__ dout,
                                                  int first, int last, int nmc) {
  const int g = blockIdx.x * 256 + threadIdx.x;
  const int P = g >> 2, cg = g & 3;          // pixel, channel-group
  const int b = P >> 12, n = P & 4095;

  float pair[21];
#pragma unroll
  for (int c = 0; c < 21; ++c) pair[c] = 0.f;

  if (!first) {
    float dots[21], dotb[21];
#pragma unroll
    for (int c = 0; c < 21; ++c) { dots[c] = 0.f; dotb[c] = 0.f; }
    float sn = 0.f, bn = 0.f;
    const size_t cst = (size_t)BB * 2 * PCH * NN;   // chunk stride (f32)
#pragma unroll
    for (int i = 0; i < 6; ++i) {
      const int k = cg + 4 * i;
      if (k > 21) continue;
      const float* ps = part + (((size_t)b * 2) * PCH + k) * NN + n;
      float s_ = 0.f, b_ = 0.f;
      for (int ch = 0; ch < nmc; ++ch) {
        s_ += ps[(size_t)ch * cst];
        b_ += ps[(size_t)ch * cst + (size_t)PCH * NN];
      }
      if (k == 21) {
        sn = s_; bn = b_;
      } else {
        const float* w = CW + (size_t)k * CWR;
        const float* v = CW + (size_t)(21 + k) * CWR;
        float wv[21], vv[21];
        *(float4*)&wv[0]  = *(const float4*)(w);
        *(float4*)&wv[4]  = *(const float4*)(w + 4);
        *(float4*)&wv[8]  = *(const float4*)(w + 8);
        *(float4*)&wv[12] = *(const float4*)(w + 12);
        *(float4*)&wv[16] = *(const float4*)(w + 16);
        wv[20] = w[20];
        *(float4*)&vv[0]  = *(const float4*)(v);
        *(float4*)&vv[4]  = *(const float4*)(v + 4);
        *(float4*)&vv[8]  = *(const float4*)(v + 8);
        *(float4*)&vv[12] = *(const float4*)(v + 12);
        *(float4*)&vv[16] = *(const float4*)(v + 16);
        vv[20] = v[20];
#pragma unroll
        for (int c = 0; c < 21; ++c) {
          dots[c] = fmaf(wv[c], s_, dots[c]);
          dotb[c] = fmaf(vv[c], b_, dotb[c]);
        }
      }
    }
    // norms live only on cg==1 lanes; butterfly gives all lanes the totals
    sn += __shfl_xor(sn, 1); sn += __shfl_xor(sn, 2);
    bn += __shfl_xor(bn, 1); bn += __shfl_xor(bn, 2);
    const float isn = 1.f / sn, ibn = 1.f / bn;
#pragma unroll
    for (int c = 0; c < 21; ++c) {
      float vv2 = fmaf(dots[c], isn, dotb[c] * ibn);
      vv2 += __shfl_xor(vv2, 1);
      vv2 += __shfl_xor(vv2, 2);
      pair[c] = vv2;
    }
  }

  if (cg == 0) {   // one lane per pixel does q/softmax/writes (static indexing)
    const float* up = unary + (size_t)P * CC;
    float q[21];
#pragma unroll
    for (int c = 0; c < 21; ++c) q[c] = up[c] - pair[c];

    if (last) {
      float* op = dout + (size_t)P * CC;
#pragma unroll
      for (int c = 0; c < 21; ++c) op[c] = q[c];
    }

    float mx = q[0];
#pragma unroll
    for (int c = 1; c < 21; ++c) mx = fmaxf(mx, q[c]);
    float e[21], s = 0.f;
#pragma unroll
    for (int c = 0; c < 21; ++c) { e[c] = __expf(q[c] - mx); s += e[c]; }
    const float is = 1.f / s;

    const float* rg = rgb + (size_t)P * 3;
    const float g0 = rg[0] * SB_SCALE, g1 = rg[1] * SB_SCALE, g2 = rg[2] * SB_SCALE;
    *(float4*)(grec + (size_t)P * 4) =
        make_float4(g0, g1, g2, -fmaf(g2, g2, fmaf(g1, g1, g0 * g0)));

    _Float16* pb = pB + (size_t)b * PCH * NN + n;
#pragma unroll
    for (int c = 0; c < 21; ++c) pb[(size_t)c * NN] = (_Float16)(e[c] * is);
    pb[(size_t)21 * NN] = (_Float16)1.0f;
  }
}

extern "C" void kernel_launch(void* const* d_in, const int* in_sizes, int n_in,
                              void* d_out, int out_size, void* d_ws, size_t ws_size,
                              hipStream_t stream) {
  const float* unary = (const float*)d_in[0];
  const float* rgb   = (const float*)d_in[1];
  const float* Ws    = (const float*)d_in[2];
  const float* Wb    = (const float*)d_in[3];
  const float* Cm    = (const float*)d_in[4];
  float* out = (float*)d_out;

  float* grec = (float*)d_ws;                                 // [B][N][4] f32 = 256 KB
  const size_t grec_bytes = (size_t)BB * NN * 4 * 4;
  _Float16* pB = (_Float16*)((char*)d_ws + grec_bytes);       // [B][22][N] f16 = 736 KB
  const size_t pB_bytes = (size_t)BB * PCH * NN * 2;

  int nmc = 8;
  const size_t cw_bytes = (size_t)2 * 21 * CWR * 4;
  while (nmc > 1 &&
         ws_size < grec_bytes + pB_bytes + cw_bytes + (size_t)nmc * BB * 2 * PCH * NN * 4)
    nmc >>= 1;
  const int mlen = NN / nmc;
  float* part = (float*)((char*)d_ws + grec_bytes + pB_bytes); // [nmc][B][2][22][N]
  float* CW = part + (size_t)nmc * BB * 2 * PCH * NN;          // [2][21][24]

  crf_prep<<<dim3(1), dim3(512), 0, stream>>>(Ws, Wb, Cm, CW);
  crf_update<<<dim3(256), dim3(256), 0, stream>>>(unary, rgb, CW, part, grec, pB,
                                                  out, 1, 0, nmc);
  for (int it = 0; it < NITER; ++it) {
    crf_filter<<<dim3(nmc, 32, BB), dim3(256), 0, stream>>>(grec, pB, part, mlen, nmc);
    crf_update<<<dim3(256), dim3(256), 0, stream>>>(unary, rgb, CW, part, grec, pB,
                                                    out, 0, (it == NITER - 1) ? 1 : 0, nmc);
  }
}